// Round 10
// baseline (351.393 us; speedup 1.0000x reference)
//
#include <hip/hip_runtime.h>
#include <stdint.h>

// VQ argmin, bit-replicating numpy fp32 reference (see R2).
// R10: 512-thread block with launch_bounds(512,1): 2 waves/SIMD (R6's proven
// latency-hiding) AND 256-VGPR cap (R7's proven no-spill for the 16x8 tile).
// Thread tile 16px x 8codes -> 6 b128 per 128 FMA-instr (b128 ~12cyc issue
// regardless of banking — R9 falsified the swizzle theory). LDS/VALU per
// phase = 576/512 cyc -> ~89% VALUBusy, floor ~123us. KT=8 DMA dbuf, SPLIT=4.
// Epilogue: shfl_xor butterfly -> 8KB LDS -> u64-key atomicMin -> gather.
// B=16 D=256 H=W=32 -> n=16384 pixels; K=2048 codes.

#define D_    256
#define K_    2048
#define HW_   1024
#define MT    128     // pixels per block
#define NT    512     // codes per block slice (one chunk)
#define KT    8       // dims per phase
#define SPLIT 4
#define KS    (K_ / SPLIT)    // 512
#define CST   516     // c row stride (floats): 16B-aligned rows
#define ZSZ   (KT * MT)             // 1024
#define BUFSZ (ZSZ + KT * CST)      // 5152 floats per buffer
#define NPIX  16384

// global -> LDS direct DMA, 16 B per lane, wave-uniform LDS base
__device__ __forceinline__ void gload16(const float* g, float* l) {
    auto* gp = reinterpret_cast<const __attribute__((address_space(1))) uint32_t*>(
        reinterpret_cast<uintptr_t>(g));
    auto* lp = reinterpret_cast<__attribute__((address_space(3))) uint32_t*>(
        reinterpret_cast<uintptr_t>(l));
    __builtin_amdgcn_global_load_lds(gp, lp, 16, 0, 0);
}

// numpy pairwise combine of 8 accumulators
__device__ __forceinline__ float pw8(const float r[8]) {
    float t01 = __fadd_rn(r[0], r[1]);
    float t23 = __fadd_rn(r[2], r[3]);
    float L   = __fadd_rn(t01, t23);
    float t45 = __fadd_rn(r[4], r[5]);
    float t67 = __fadd_rn(r[6], r[7]);
    float R   = __fadd_rn(t45, t67);
    return __fadd_rn(L, R);
}

// prep: [0,128) transpose cb->ct (+blk0 zeroes cnt); [128,136) Bn;
//       [136,264) An via exact half-split + keys init
__global__ __launch_bounds__(256) void prep_k(const float* __restrict__ z,
                                              const float* __restrict__ cb,
                                              float* __restrict__ ct,
                                              float* __restrict__ An,
                                              float* __restrict__ Bn,
                                              unsigned long long* __restrict__ keys,
                                              int* __restrict__ cnt) {
    __shared__ float t[64][65];
    __shared__ float hs[2][128];
    int tid = threadIdx.x;
    int bx  = blockIdx.x;
    if (bx < 128) {
        if (bx == 0 && tid < MT) cnt[tid] = 0;   // 128 pixel-blocks
        int k0 = (bx & 31) << 6;
        int d0 = (bx >> 5) << 6;
        #pragma unroll
        for (int it = 0; it < 4; ++it) {
            int u  = (it << 8) + tid;
            int kk = u >> 4;
            int dd = (u & 15) << 2;
            float4 v = *reinterpret_cast<const float4*>(
                cb + (size_t)(k0 + kk) * D_ + d0 + dd);
            t[kk][dd + 0] = v.x; t[kk][dd + 1] = v.y;
            t[kk][dd + 2] = v.z; t[kk][dd + 3] = v.w;
        }
        __syncthreads();
        #pragma unroll
        for (int it = 0; it < 4; ++it) {
            int u  = (it << 8) + tid;
            int dd = u >> 4;
            int kk = (u & 15) << 2;
            float4 o;
            o.x = t[kk + 0][dd]; o.y = t[kk + 1][dd];
            o.z = t[kk + 2][dd]; o.w = t[kk + 3][dd];
            *reinterpret_cast<float4*>(ct + (size_t)(d0 + dd) * K_ + k0 + kk) = o;
        }
    } else if (bx < 136) {
        int row = (bx - 128) * 256 + tid;
        const float4* p = reinterpret_cast<const float4*>(cb + (size_t)row * D_);
        float rA[8], rB[8];
        #pragma unroll
        for (int j = 0; j < 8; ++j) { rA[j] = 0.f; rB[j] = 0.f; }
        #pragma unroll
        for (int q = 0; q < 64; ++q) {
            float4 v = p[q];
            float pv[4] = {__fmul_rn(v.x, v.x), __fmul_rn(v.y, v.y),
                           __fmul_rn(v.z, v.z), __fmul_rn(v.w, v.w)};
            if (q < 32) {
                #pragma unroll
                for (int l = 0; l < 4; ++l)
                    rA[(4 * q + l) & 7] = __fadd_rn(rA[(4 * q + l) & 7], pv[l]);
            } else {
                #pragma unroll
                for (int l = 0; l < 4; ++l)
                    rB[(4 * q + l) & 7] = __fadd_rn(rB[(4 * q + l) & 7], pv[l]);
            }
        }
        Bn[row] = __fadd_rn(pw8(rA), pw8(rB));
    } else {
        int blk = bx - 136;                  // [0,128): 128 pixels each
        int b   = blk >> 3;
        int hw0 = (blk & 7) << 7;
        int px  = tid & 127;
        int h   = tid >> 7;                  // dim-half
        if (h == 0) keys[(size_t)b * HW_ + hw0 + px] = 0xFFFFFFFFFFFFFFFFull;
        const float* zb = z + (size_t)b * (D_ * HW_) + hw0 + px
                            + (size_t)h * 128 * HW_;
        float r[8];
        #pragma unroll
        for (int j = 0; j < 8; ++j) r[j] = 0.f;
        #pragma unroll 8
        for (int d = 0; d < 128; ++d) {      // position-in-half == d&7 exact
            float v = zb[(size_t)d * HW_];
            r[d & 7] = __fadd_rn(r[d & 7], __fmul_rn(v, v));
        }
        hs[h][px] = pw8(r);
        __syncthreads();
        if (tid < 128)
            An[(size_t)b * HW_ + hw0 + tid] = __fadd_rn(hs[0][tid], hs[1][tid]);
    }
}

// main GEMM+argmin: 8-wave block, 16x8 tile, DMA dbuf, butterfly+atomic merge
__global__ __launch_bounds__(512, 1) void vq_k(const float* __restrict__ z,
                                               const float* __restrict__ ct,
                                               const float* __restrict__ cb,
                                               const float* __restrict__ An,
                                               const float* __restrict__ Bn,
                                               unsigned long long* __restrict__ keys,
                                               int* __restrict__ cnt,
                                               float* __restrict__ out) {
    __shared__ __align__(16) float smem[2 * BUFSZ];   // 41216 B
    __shared__ int idxs[MT];
    __shared__ int sflag;

    const int tid  = threadIdx.x;
    const int lane = tid & 63;
    const int w    = tid >> 6;               // wave id [0,8)
    const int c8   = tid & 7;
    const int g    = (tid >> 3) & 7;         // pixel-group [0,8)
    const int c    = (w << 3) | c8;          // code-group [0,64)
    const int blk  = blockIdx.x;
    const int p    = blk >> 2;               // pixel-block [0,128)
    const int s    = blk & 3;                // K-split slice
    const int b      = p >> 3;
    const int hwbase = (p & 7) << 7;         // 128 pixels
    const float* zbase = z + (size_t)b * (D_ * HW_) + hwbase;
    const float* ctS   = ct + s * KS;

    // per-lane DMA sources: z gload covers 2 dim-rows x 128 px; c gload 256 floats
    const float* zsrc = zbase + (size_t)(lane >> 5) * HW_ + ((lane & 31) << 2);
    const float* csrc = ctS + ((size_t)lane << 2);

    float acc[16][8];
    #pragma unroll
    for (int i = 0; i < 16; ++i)
        #pragma unroll
        for (int j = 0; j < 8; ++j) acc[i][j] = 0.f;

    // stage phase ph into buf[ph&1]: waves 0-3 one z-DMA each; all waves 2 c-DMAs
    #define STAGE(ph)                                                         \
        do {                                                                  \
            int buf_ = (ph) & 1;                                              \
            float* zb_ = smem + buf_ * BUFSZ;                                 \
            float* cd_ = zb_ + ZSZ;                                           \
            if (w < 4)                                                        \
                gload16(zsrc + (size_t)((ph) * KT + (w << 1)) * HW_,          \
                        zb_ + (w << 1) * MT);                                 \
            gload16(csrc + (size_t)((ph) * KT + w) * K_,       cd_ + w * CST);\
            gload16(csrc + (size_t)((ph) * KT + w) * K_ + 256,                \
                    cd_ + w * CST + 256);                                     \
        } while (0)

    STAGE(0);

    for (int ph = 0; ph < 32; ++ph) {
        __syncthreads();              // drains phase-ph DMA (issued 1 phase ago)
        if (ph < 31) STAGE(ph + 1);   // other buffer; hidden behind FMA below
        const float* zb_ = smem + (ph & 1) * BUFSZ;
        const float* cd_ = zb_ + ZSZ;
        // ascending-k single-acc FMA chain — bit-matches sgemm
        #pragma unroll
        for (int d = 0; d < KT; ++d) {
            const float* zr = zb_ + d * MT + (g << 2);   // 128B wave span/quad
            float4 a0 = *reinterpret_cast<const float4*>(zr);
            float4 a1 = *reinterpret_cast<const float4*>(zr + 32);
            float4 a2 = *reinterpret_cast<const float4*>(zr + 64);
            float4 a3 = *reinterpret_cast<const float4*>(zr + 96);
            const float* cr = cd_ + d * CST + (c << 2);
            float4 b0 = *reinterpret_cast<const float4*>(cr);
            float4 b1 = *reinterpret_cast<const float4*>(cr + 256);
            float av[16] = {a0.x, a0.y, a0.z, a0.w, a1.x, a1.y, a1.z, a1.w,
                            a2.x, a2.y, a2.z, a2.w, a3.x, a3.y, a3.z, a3.w};
            float bv[8]  = {b0.x, b0.y, b0.z, b0.w, b1.x, b1.y, b1.z, b1.w};
            #pragma unroll
            for (int i = 0; i < 16; ++i)
                #pragma unroll
                for (int j = 0; j < 8; ++j)
                    acc[i][j] = fmaf(av[i], bv[j], acc[i][j]);
        }
    }
    #undef STAGE

    // fold: d = fp32( fp32(A+B) - 2*M ); u64 keys give exact first-min
    float an[16];
    #pragma unroll
    for (int i = 0; i < 16; ++i) {
        int m = ((i >> 2) << 5) + (g << 2) + (i & 3);   // pixel q*32+g*4+i4
        an[i] = An[(size_t)b * HW_ + hwbase + m];
    }
    unsigned long long kmin[16];
    #pragma unroll
    for (int i = 0; i < 16; ++i) kmin[i] = 0xFFFFFFFFFFFFFFFFull;
    #pragma unroll
    for (int j = 0; j < 8; ++j) {
        int ng = s * KS + ((j >> 2) << 8) + (c << 2) + (j & 3);
        float bn = Bn[ng];
        #pragma unroll
        for (int i = 0; i < 16; ++i) {
            float sc = __fsub_rn(__fadd_rn(an[i], bn),
                                 __fmul_rn(2.0f, acc[i][j]));
            // sc > 0 always -> fp32 bit pattern is order-preserving
            unsigned long long key =
                ((unsigned long long)__float_as_uint(sc) << 32) | (unsigned)ng;
            if (key < kmin[i]) kmin[i] = key;
        }
    }
    // in-wave butterfly over the 8 c8-groups (same pixels, disjoint codes)
    #pragma unroll
    for (int i = 0; i < 16; ++i) {
        unsigned long long k = kmin[i], o;
        o = __shfl_xor(k, 1, 64); if (o < k) k = o;
        o = __shfl_xor(k, 2, 64); if (o < k) k = o;
        o = __shfl_xor(k, 4, 64); if (o < k) k = o;
        kmin[i] = k;
    }
    __syncthreads();   // buffers dead; reuse smem as kred[128][8]
    unsigned long long* kred = reinterpret_cast<unsigned long long*>(smem);
    if (c8 == 0) {
        #pragma unroll
        for (int i = 0; i < 16; ++i) {
            int m = ((i >> 2) << 5) + (g << 2) + (i & 3);
            kred[(m << 3) + w] = kmin[i];
        }
    }
    __syncthreads();
    unsigned long long* keyp = keys + (size_t)b * HW_ + hwbase;
    if (tid < MT) {
        unsigned long long k2 = kred[tid << 3];
        #pragma unroll
        for (int t = 1; t < 8; ++t) {
            unsigned long long o = kred[(tid << 3) + t];
            if (o < k2) k2 = o;
        }
        atomicMin(keyp + tid, k2);
    }
    __threadfence();
    __syncthreads();
    if (tid == 0) sflag = atomicAdd(cnt + p, 1);
    __syncthreads();
    if (sflag == SPLIT - 1) {         // last split: gather + store 128 pixels
        if (tid < MT) {
            unsigned long long v = atomicMin(keyp + tid, 0xFFFFFFFFFFFFFFFFull);
            idxs[tid] = (int)(unsigned)v;
        }
        __syncthreads();
        float* obase = out + (size_t)b * (D_ * HW_) + hwbase;
        #pragma unroll
        for (int it = 0; it < 16; ++it) {
            int uu = (it << 9) + tid;
            int dd = uu >> 5;         // [0,256)
            int c4 = uu & 31;         // float4 column among 128 pixels
            int i0 = idxs[(c4 << 2) + 0];
            int i1 = idxs[(c4 << 2) + 1];
            int i2 = idxs[(c4 << 2) + 2];
            int i3 = idxs[(c4 << 2) + 3];
            float4 o;
            o.x = cb[(size_t)i0 * D_ + dd];
            o.y = cb[(size_t)i1 * D_ + dd];
            o.z = cb[(size_t)i2 * D_ + dd];
            o.w = cb[(size_t)i3 * D_ + dd];
            *reinterpret_cast<float4*>(obase + (size_t)dd * HW_ + (c4 << 2)) = o;
        }
    }
}

extern "C" void kernel_launch(void* const* d_in, const int* in_sizes, int n_in,
                              void* d_out, int out_size, void* d_ws, size_t ws_size,
                              hipStream_t stream) {
    const float* z  = (const float*)d_in[0];   // 16*256*32*32
    const float* cb = (const float*)d_in[1];   // 2048*256
    unsigned long long* keys = (unsigned long long*)d_ws;   // 16384
    int*   cnt = (int*)(keys + NPIX);                       // 128
    float* An  = (float*)(cnt + 128);                       // 16384
    float* Bn  = An + NPIX;                                 // 2048
    float* ct  = Bn + K_;                                   // 256*2048 (2 MB)
    float* out = (float*)d_out;

    prep_k<<<dim3(264), dim3(256), 0, stream>>>(z, cb, ct, An, Bn, keys, cnt);
    vq_k<<<dim3(128 * SPLIT), dim3(512), 0, stream>>>(z, ct, cb, An, Bn,
                                                      keys, cnt, out);
}